// Round 1
// baseline (323.528 us; speedup 1.0000x reference)
//
#include <hip/hip_runtime.h>
#include <math.h>

#define NN 100000
#define NE 640000
#define ET (NE + NN)          // edges + self loops = 740000
#define FIN 128
#define C1 64
#define C2 16
#define NEG_SLOPE 0.2f
#define SCAN_B 1024
#define SCAN_NB ((NN + SCAN_B - 1) / SCAN_B)   // 98

static __device__ __forceinline__ float lrelu(float x) { return x > 0.f ? x : NEG_SLOPE * x; }
static __device__ __forceinline__ float softplusf(float x) {
    return fmaxf(x, 0.f) + log1pf(expf(-fabsf(x)));
}

// ---------------- CSR build ----------------
__global__ void k_zero(int* __restrict__ deg, int* __restrict__ cnt) {
    int i = blockIdx.x * blockDim.x + threadIdx.x;
    if (i < NN) { deg[i] = 0; cnt[i] = 0; }
}

__global__ void k_hist(const int* __restrict__ ei, int* __restrict__ deg) {
    int i = blockIdx.x * blockDim.x + threadIdx.x;
    if (i >= ET) return;
    int dst = (i < NE) ? ei[NE + i] : (i - NE);
    atomicAdd(&deg[dst], 1);
}

__global__ void k_scan1(const int* __restrict__ deg, int* __restrict__ incl, int* __restrict__ bsum) {
    __shared__ int s[SCAN_B];
    int ti = threadIdx.x;
    int i = blockIdx.x * SCAN_B + ti;
    int v = (i < NN) ? deg[i] : 0;
    s[ti] = v; __syncthreads();
    for (int d = 1; d < SCAN_B; d <<= 1) {
        int t = (ti >= d) ? s[ti - d] : 0;
        __syncthreads();
        s[ti] += t;
        __syncthreads();
    }
    if (i < NN) incl[i] = s[ti];
    if (ti == SCAN_B - 1) bsum[blockIdx.x] = s[ti];
}

__global__ void k_scan2(const int* __restrict__ bsum, int* __restrict__ boff) {
    if (threadIdx.x == 0 && blockIdx.x == 0) {
        int r = 0;
        for (int j = 0; j < SCAN_NB; j++) { boff[j] = r; r += bsum[j]; }
    }
}

__global__ void k_scan3(const int* __restrict__ incl, const int* __restrict__ boff, int* __restrict__ rowptr) {
    int i = blockIdx.x * blockDim.x + threadIdx.x;
    if (i < NN) rowptr[i + 1] = incl[i] + boff[i >> 10];
    if (i == 0) rowptr[0] = 0;
}

__global__ void k_scatter(const int* __restrict__ ei, const int* __restrict__ rowptr,
                          int* __restrict__ cnt, int* __restrict__ csr_src) {
    int i = blockIdx.x * blockDim.x + threadIdx.x;
    if (i >= ET) return;
    int src, dst;
    if (i < NE) { src = ei[i]; dst = ei[NE + i]; }
    else        { src = i - NE; dst = src; }
    int pos = rowptr[dst] + atomicAdd(&cnt[dst], 1);
    csr_src[pos] = src;
}

// ---------------- Layer 1 GEMM: h1 = x @ W1, + attention dots ----------------
#define K3_RPW 16
__global__ __launch_bounds__(256, 2) void k_gemm1(
        const float* __restrict__ x, const float* __restrict__ W1,
        const float* __restrict__ attS, const float* __restrict__ attD,
        float* __restrict__ h1, float* __restrict__ as1, float* __restrict__ ad1) {
    __shared__ float xbuf[4][FIN];
    int lane = threadIdx.x & 63;
    int wv = threadIdx.x >> 6;
    int base = (blockIdx.x * 4 + wv) * K3_RPW;
    if (base >= NN) return;
    float w[FIN];
#pragma unroll
    for (int k = 0; k < FIN; k++) w[k] = W1[k * C1 + lane];
    float ats = attS[lane], atd = attD[lane];
    for (int r = 0; r < K3_RPW; r++) {
        int n = base + r;
        if (n >= NN) break;
        float2 xv = *reinterpret_cast<const float2*>(&x[(size_t)n * FIN + lane * 2]);
        *reinterpret_cast<float2*>(&xbuf[wv][lane * 2]) = xv;
        __builtin_amdgcn_wave_barrier();
        float acc = 0.f;
#pragma unroll
        for (int k4 = 0; k4 < FIN / 4; k4++) {
            float4 xk = *reinterpret_cast<const float4*>(&xbuf[wv][k4 * 4]);
            acc = fmaf(xk.x, w[k4 * 4 + 0], acc);
            acc = fmaf(xk.y, w[k4 * 4 + 1], acc);
            acc = fmaf(xk.z, w[k4 * 4 + 2], acc);
            acc = fmaf(xk.w, w[k4 * 4 + 3], acc);
        }
        __builtin_amdgcn_wave_barrier();
        h1[(size_t)n * C1 + lane] = acc;
        float s1 = acc * ats, d1 = acc * atd;
#pragma unroll
        for (int off = 32; off; off >>= 1) {
            s1 += __shfl_xor(s1, off);
            d1 += __shfl_xor(d1, off);
        }
        if (lane == 0) { as1[n] = s1; ad1[n] = d1; }
    }
}

// ---------------- Layer 1 aggregate + bias + ixz1 + elu ----------------
__global__ __launch_bounds__(256, 4) void k_agg1(
        const int* __restrict__ rowptr, const int* __restrict__ csr_src,
        const float* __restrict__ h1, const float* __restrict__ as1, const float* __restrict__ ad1,
        const float* __restrict__ b1,
        float* __restrict__ helu, float* __restrict__ ixz1) {
    int lane = threadIdx.x & 63;
    int node = (blockIdx.x * blockDim.x + threadIdx.x) >> 6;
    if (node >= NN) return;
    int start = rowptr[node], end = rowptr[node + 1];
    float adn = ad1[node];
    float m = -1e30f;
    for (int e = start + lane; e < end; e += 64) {
        int s = csr_src[e];
        m = fmaxf(m, lrelu(as1[s] + adn));
    }
#pragma unroll
    for (int off = 32; off; off >>= 1) m = fmaxf(m, __shfl_xor(m, off));
    float acc = 0.f, den = 0.f;
    for (int e = start; e < end; e++) {
        int s = csr_src[e];
        float a = lrelu(as1[s] + adn);
        float wgt = expf(a - m);
        den += wgt;
        acc += wgt * h1[(size_t)s * C1 + lane];
    }
    float out = acc / (den + 1e-16f) + b1[lane];
    helu[(size_t)node * C1 + lane] = out > 0.f ? out : expm1f(out);
    float other = __shfl_down(out, 32);
    if (lane < 32) {
        float sd = softplusf(other) + 1e-10f;
        float kl = -logf(sd) + 0.5f * (sd * sd + out * out - 1.f);
        ixz1[(size_t)node * 32 + lane] = kl;
    }
}

// ---------------- Layer 2 GEMM: h2 = helu @ W2, + attention dots ----------------
__global__ __launch_bounds__(256, 4) void k_gemm2(
        const float* __restrict__ helu, const float* __restrict__ W2,
        const float* __restrict__ attS, const float* __restrict__ attD,
        float* __restrict__ h2, float* __restrict__ as2, float* __restrict__ ad2) {
    int lane = threadIdx.x & 63;
    int wv = threadIdx.x >> 6;
    int f = lane & 15, rg = lane >> 4;
    int n0 = (blockIdx.x * 4 + wv) * 4;
    if (n0 >= NN) return;
    float w[C1];
#pragma unroll
    for (int k = 0; k < C1; k++) w[k] = W2[k * C2 + f];
    int n = n0 + rg;
    bool valid = n < NN;
    float acc = 0.f;
    if (valid) {
        const float* xr = &helu[(size_t)n * C1];
#pragma unroll
        for (int k4 = 0; k4 < C1 / 4; k4++) {
            float4 xk = *reinterpret_cast<const float4*>(&xr[k4 * 4]);
            acc = fmaf(xk.x, w[k4 * 4 + 0], acc);
            acc = fmaf(xk.y, w[k4 * 4 + 1], acc);
            acc = fmaf(xk.z, w[k4 * 4 + 2], acc);
            acc = fmaf(xk.w, w[k4 * 4 + 3], acc);
        }
        h2[(size_t)n * C2 + f] = acc;
    }
    float s1 = acc * attS[f], d1 = acc * attD[f];
#pragma unroll
    for (int off = 1; off < 16; off <<= 1) {
        s1 += __shfl_xor(s1, off);
        d1 += __shfl_xor(d1, off);
    }
    if (valid && f == 0) { as2[n] = s1; ad2[n] = d1; }
}

// ---------------- Layer 2 aggregate + bias + out2 + ixz2 ----------------
__global__ __launch_bounds__(256, 4) void k_agg2(
        const int* __restrict__ rowptr, const int* __restrict__ csr_src,
        const float* __restrict__ h2, const float* __restrict__ as2, const float* __restrict__ ad2,
        const float* __restrict__ b2,
        float* __restrict__ out2, float* __restrict__ ixz2) {
    int lane = threadIdx.x & 63;
    int node = (blockIdx.x * blockDim.x + threadIdx.x) >> 6;
    if (node >= NN) return;
    int start = rowptr[node], end = rowptr[node + 1];
    float adn = ad2[node];
    float m = -1e30f;
    for (int e = start + lane; e < end; e += 64) {
        int s = csr_src[e];
        m = fmaxf(m, lrelu(as2[s] + adn));
    }
#pragma unroll
    for (int off = 32; off; off >>= 1) m = fmaxf(m, __shfl_xor(m, off));
    int f = lane & 15, g = lane >> 4;
    float acc = 0.f, den = 0.f;
    for (int e0 = start; e0 < end; e0 += 4) {
        int e = e0 + g;
        if (e < end) {
            int s = csr_src[e];
            float a = lrelu(as2[s] + adn);
            float wgt = expf(a - m);
            den += wgt;
            acc += wgt * h2[(size_t)s * C2 + f];
        }
    }
    acc += __shfl_xor(acc, 16); acc += __shfl_xor(acc, 32);
    den += __shfl_xor(den, 16); den += __shfl_xor(den, 32);
    float out = acc / (den + 1e-16f) + b2[f];
    if (lane < 16) out2[(size_t)node * C2 + f] = out;
    float other = __shfl_down(out, 8);
    if (lane < 8) {
        float sd = softplusf(other) + 1e-10f;
        float kl = -logf(sd) + 0.5f * (sd * sd + out * out - 1.f);
        ixz2[(size_t)node * 8 + lane] = kl;
    }
}

extern "C" void kernel_launch(void* const* d_in, const int* in_sizes, int n_in,
                              void* d_out, int out_size, void* d_ws, size_t ws_size,
                              hipStream_t stream) {
    const float* x     = (const float*)d_in[0];
    const int*   ei    = (const int*)d_in[1];
    const float* W1    = (const float*)d_in[2];
    const float* aS1   = (const float*)d_in[3];
    const float* aD1   = (const float*)d_in[4];
    const float* b1    = (const float*)d_in[5];
    const float* W2    = (const float*)d_in[6];
    const float* aS2   = (const float*)d_in[7];
    const float* aD2   = (const float*)d_in[8];
    const float* b2    = (const float*)d_in[9];

    float* out = (float*)d_out;
    float* out2 = out;                         // N*16
    float* ixz1 = out + (size_t)NN * C2;       // N*32
    float* ixz2 = ixz1 + (size_t)NN * 32;      // N*8

    char* p = (char*)d_ws;
    auto alloc = [&](size_t bytes) -> void* {
        void* r = (void*)p;
        p += (bytes + 255) & ~(size_t)255;
        return r;
    };
    int* deg     = (int*)alloc((size_t)NN * 4);
    int* cnt     = (int*)alloc((size_t)NN * 4);
    int* incl    = (int*)alloc((size_t)NN * 4);
    int* bsum    = (int*)alloc(512 * 4);
    int* boff    = (int*)alloc(512 * 4);
    int* rowptr  = (int*)alloc((size_t)(NN + 1) * 4);
    int* csr_src = (int*)alloc((size_t)ET * 4);
    float* h1    = (float*)alloc((size_t)NN * C1 * 4);
    float* as1   = (float*)alloc((size_t)NN * 4);
    float* ad1   = (float*)alloc((size_t)NN * 4);
    float* helu  = (float*)alloc((size_t)NN * C1 * 4);
    float* h2    = (float*)alloc((size_t)NN * C2 * 4);
    float* as2   = (float*)alloc((size_t)NN * 4);
    float* ad2   = (float*)alloc((size_t)NN * 4);
    (void)ws_size; (void)in_sizes; (void)n_in; (void)out_size;

    // CSR build
    k_zero<<<(NN + 255) / 256, 256, 0, stream>>>(deg, cnt);
    k_hist<<<(ET + 255) / 256, 256, 0, stream>>>(ei, deg);
    k_scan1<<<SCAN_NB, SCAN_B, 0, stream>>>(deg, incl, bsum);
    k_scan2<<<1, 64, 0, stream>>>(bsum, boff);
    k_scan3<<<(NN + 255) / 256, 256, 0, stream>>>(incl, boff, rowptr);
    k_scatter<<<(ET + 255) / 256, 256, 0, stream>>>(ei, rowptr, cnt, csr_src);

    // Layer 1
    k_gemm1<<<(NN + 4 * K3_RPW - 1) / (4 * K3_RPW), 256, 0, stream>>>(x, W1, aS1, aD1, h1, as1, ad1);
    k_agg1<<<(NN + 3) / 4, 256, 0, stream>>>(rowptr, csr_src, h1, as1, ad1, b1, helu, ixz1);

    // Layer 2
    k_gemm2<<<(NN + 15) / 16, 256, 0, stream>>>(helu, W2, aS2, aD2, h2, as2, ad2);
    k_agg2<<<(NN + 3) / 4, 256, 0, stream>>>(rowptr, csr_src, h2, as2, ad2, b2, out2, ixz2);
}